// Round 1
// baseline (270.548 us; speedup 1.0000x reference)
//
#include <hip/hip_runtime.h>
#include <hip/hip_bf16.h>

// Problem: B=8, N=4096, M=2048, IN=512, D=512, CTX=768
// out = h + attn @ f2,  attn = softmax(h W_a^T),  f2^T = W_out W_v G W_k^T,
// G = X^T X (symmetric), X = [h; h_retrieved W_c^T]  (all bf16 MFMA internally)

typedef unsigned short u16;
typedef __bf16 bf16x8 __attribute__((ext_vector_type(8)));
typedef float  f32x4  __attribute__((ext_vector_type(4)));
typedef float  f32v4  __attribute__((ext_vector_type(4)));
typedef u16    u16v4  __attribute__((ext_vector_type(4)));
typedef u16    u16v8  __attribute__((ext_vector_type(8)));

__device__ __forceinline__ u16 f2bf(float f) {
  unsigned u = __builtin_bit_cast(unsigned, f);
  u = u + 0x7FFFu + ((u >> 16) & 1u);   // RNE; inputs are finite
  return (u16)(u >> 16);
}
__device__ __forceinline__ float bf2f(u16 s) {
  return __builtin_bit_cast(float, (unsigned)s << 16);
}

// ---------------- elementwise f32 -> bf16 ----------------
__global__ __launch_bounds__(256) void cvt_f32_bf16(const float* __restrict__ in,
                                                    u16* __restrict__ out, long n) {
  long i = (((long)blockIdx.x * 256) + threadIdx.x) * 8;
  if (i >= n) return;
  f32v4 a = *(const f32v4*)(in + i);
  f32v4 b = *(const f32v4*)(in + i + 4);
  u16v8 o;
  o[0] = f2bf(a[0]); o[1] = f2bf(a[1]); o[2] = f2bf(a[2]); o[3] = f2bf(a[3]);
  o[4] = f2bf(b[0]); o[5] = f2bf(b[1]); o[6] = f2bf(b[2]); o[7] = f2bf(b[3]);
  *(u16v8*)(out + i) = o;
}

// ---------------- tiled bf16 transpose: dst[c,r] = src[r,c] ----------------
__global__ __launch_bounds__(256) void transpose_bf16(const u16* __restrict__ src,
                                                      u16* __restrict__ dst,
                                                      int src_ld, int dst_ld,
                                                      long src_bs, long dst_bs) {
  __shared__ u16 tile[64][72];   // +8 pad breaks bank conflicts
  long b = blockIdx.z;
  const u16* S = src + b * src_bs;
  u16* D = dst + b * dst_bs;
  int r0 = blockIdx.x * 64;
  int c0 = blockIdx.y * 64;
  int t  = threadIdx.x;
  int tr = t >> 3;          // 0..31
  int tc = (t & 7) * 8;     // 0..56
#pragma unroll
  for (int it = 0; it < 2; ++it) {
    int rr = it * 32 + tr;
    *(u16v8*)&tile[rr][tc] = *(const u16v8*)&S[(long)(r0 + rr) * src_ld + c0 + tc];
  }
  __syncthreads();
#pragma unroll
  for (int it = 0; it < 2; ++it) {
    int cr = it * 32 + tr;
    u16v8 o;
#pragma unroll
    for (int j = 0; j < 8; ++j) o[j] = tile[tc + j][cr];
    *(u16v8*)&D[(long)(c0 + cr) * dst_ld + r0 + tc] = o;
  }
}

// ---------------- row softmax over 512 bf16 (in place), 1 wave/row ----------------
__global__ __launch_bounds__(256) void softmax512(u16* __restrict__ data) {
  long row = (long)blockIdx.x * 4 + (threadIdx.x >> 6);
  int lane = threadIdx.x & 63;
  u16* p = data + row * 512 + lane * 8;
  u16v8 raw = *(const u16v8*)p;
  float v[8];
  float mx = -3.0e38f;
#pragma unroll
  for (int j = 0; j < 8; ++j) { v[j] = bf2f(raw[j]); mx = fmaxf(mx, v[j]); }
#pragma unroll
  for (int o = 32; o > 0; o >>= 1) mx = fmaxf(mx, __shfl_xor(mx, o, 64));
  float sm = 0.f;
#pragma unroll
  for (int j = 0; j < 8; ++j) { v[j] = __expf(v[j] - mx); sm += v[j]; }
#pragma unroll
  for (int o = 32; o > 0; o >>= 1) sm += __shfl_xor(sm, o, 64);
  float inv = 1.0f / sm;
  u16v8 ov;
#pragma unroll
  for (int j = 0; j < 8; ++j) ov[j] = f2bf(v[j] * inv);
  *(u16v8*)p = ov;
}

// ---------------- reduce 4 split-K f32 slices -> bf16 (per batch 512x512) ----------------
__global__ __launch_bounds__(256) void reduce4_bf16(const float* __restrict__ parts,
                                                    u16* __restrict__ out) {
  long i = (((long)blockIdx.x * 256) + threadIdx.x) * 4;  // 8*262144 total
  long b = i >> 18;
  long r = i & 262143;
  const float* p = parts + b * 1048576 + r;
  f32v4 s0 = *(const f32v4*)p;
  f32v4 s1 = *(const f32v4*)(p + 262144);
  f32v4 s2 = *(const f32v4*)(p + 524288);
  f32v4 s3 = *(const f32v4*)(p + 786432);
  u16v4 o;
#pragma unroll
  for (int j = 0; j < 4; ++j) o[j] = f2bf(s0[j] + s1[j] + s2[j] + s3[j]);
  *(u16v4*)(out + i) = o;
}

// ---------------- NT GEMM: C[m,n] = sum_k A[m,k]*B[n,k]  (m97 structure) ----------------
// 128x128 tile, BK=64, 256 threads (4 waves, 2x2), 16x16x32 bf16 MFMA,
// global_load_lds width-16 staging. All dims multiples of tile sizes (no tails).
// MODE: 0 = bf16 store, 1 = f32 store + f32 residual add, 2 = f32 store (split-K partials)
template <int MODE>
__global__ __launch_bounds__(256) void gemm_nt(
    const u16* __restrict__ A, const u16* __restrict__ B, void* __restrict__ Cout,
    const float* __restrict__ Res, int K, int lda, int ldb, int ldc,
    long sA, long sB, long sC, long sS, long sRes, int kslices) {
  __shared__ u16 As[128 * 64];
  __shared__ u16 Bs[128 * 64];

  int z = blockIdx.z;
  int b = z / kslices;
  int s = z - b * kslices;
  const u16* Ag = A + (long)b * sA + (long)s * K;  // k-offset within rows
  const u16* Bg = B + (long)b * sB + (long)s * K;

  long m0 = (long)blockIdx.x * 128;
  long n0 = (long)blockIdx.y * 128;

  int tid  = threadIdx.x;
  int lane = tid & 63;
  int wid  = tid >> 6;
  int wm = wid >> 1, wn = wid & 1;

  int srow = wid * 8 + (lane >> 3);   // staging: 8 rows per wave per call
  int scol = (lane & 7) * 8;          // 16B per lane

  f32x4 acc[4][4] = {};

  for (int k0 = 0; k0 < K; k0 += 64) {
#pragma unroll
    for (int c = 0; c < 4; ++c) {
      int row = c * 32 + srow;
      __builtin_amdgcn_global_load_lds(
          (const __attribute__((address_space(1))) void*)(Ag + (m0 + row) * lda + k0 + scol),
          (__attribute__((address_space(3))) void*)(As + (c * 32 + wid * 8) * 64),
          16, 0, 0);
    }
#pragma unroll
    for (int c = 0; c < 4; ++c) {
      int row = c * 32 + srow;
      __builtin_amdgcn_global_load_lds(
          (const __attribute__((address_space(1))) void*)(Bg + (n0 + row) * ldb + k0 + scol),
          (__attribute__((address_space(3))) void*)(Bs + (c * 32 + wid * 8) * 64),
          16, 0, 0);
    }
    __syncthreads();
#pragma unroll
    for (int kk = 0; kk < 2; ++kk) {
      int kofs = kk * 32 + (lane >> 4) * 8;
      bf16x8 af[4], bfr[4];
#pragma unroll
      for (int i = 0; i < 4; ++i) {
        af[i]  = *(const bf16x8*)&As[(wm * 64 + i * 16 + (lane & 15)) * 64 + kofs];
        bfr[i] = *(const bf16x8*)&Bs[(wn * 64 + i * 16 + (lane & 15)) * 64 + kofs];
      }
#pragma unroll
      for (int i = 0; i < 4; ++i)
#pragma unroll
        for (int j = 0; j < 4; ++j)
          acc[i][j] = __builtin_amdgcn_mfma_f32_16x16x32_bf16(af[i], bfr[j], acc[i][j], 0, 0, 0);
    }
    __syncthreads();
  }

  long cb  = (long)b * sC + (long)s * sS;
  int col  = (int)n0 + wn * 64 + (lane & 15);
  int row0 = (int)m0 + wm * 64 + ((lane >> 4) << 2);

  if (MODE == 0) {
    u16* C = (u16*)Cout + cb;
#pragma unroll
    for (int i = 0; i < 4; ++i)
#pragma unroll
      for (int r = 0; r < 4; ++r) {
        long rowoff = (long)(row0 + i * 16 + r) * ldc + col;
#pragma unroll
        for (int j = 0; j < 4; ++j) C[rowoff + j * 16] = f2bf(acc[i][j][r]);
      }
  } else if (MODE == 1) {
    float* C = (float*)Cout + cb;
    const float* R = Res + (long)b * sRes;
#pragma unroll
    for (int i = 0; i < 4; ++i)
#pragma unroll
      for (int r = 0; r < 4; ++r) {
        long rowoff = (long)(row0 + i * 16 + r) * ldc + col;
#pragma unroll
        for (int j = 0; j < 4; ++j) C[rowoff + j * 16] = acc[i][j][r] + R[rowoff + j * 16];
      }
  } else {
    float* C = (float*)Cout + cb;
#pragma unroll
    for (int i = 0; i < 4; ++i)
#pragma unroll
      for (int r = 0; r < 4; ++r) {
        long rowoff = (long)(row0 + i * 16 + r) * ldc + col;
#pragma unroll
        for (int j = 0; j < 4; ++j) C[rowoff + j * 16] = acc[i][j][r];
      }
  }
}

// ---------------- host ----------------
extern "C" void kernel_launch(void* const* d_in, const int* in_sizes, int n_in,
                              void* d_out, int out_size, void* d_ws, size_t ws_size,
                              hipStream_t stream) {
  (void)in_sizes; (void)n_in; (void)out_size; (void)ws_size;
  const float* h    = (const float*)d_in[0];
  const float* hret = (const float*)d_in[1];
  const float* Wc   = (const float*)d_in[2];
  const float* Wa   = (const float*)d_in[3];
  const float* Wk   = (const float*)d_in[4];
  const float* Wv   = (const float*)d_in[5];
  const float* Wo   = (const float*)d_in[6];
  float* out = (float*)d_out;
  char*  ws  = (char*)d_ws;

  constexpr long MB = 1024 * 1024;
  // workspace layout (peak 132 MB, overlay-allocated; stream order guarantees liveness)
  u16*   w_cond = (u16*)(ws + 0);
  u16*   w_attn = (u16*)(ws + 786432);
  u16*   w_k    = (u16*)(ws + 1310720);
  u16*   w_v    = (u16*)(ws + 1835008);
  u16*   w_out  = (u16*)(ws + 2359296);
  u16*   w_vT   = (u16*)(ws + 2883584);
  u16*   h_bf   = (u16*)(ws + 4 * MB);    // 32MB  [live: cvt .. XT build]
  u16*   attn   = (u16*)(ws + 36 * MB);   // 32MB  [live: logits .. final]
  u16*   hr_bf  = (u16*)(ws + 68 * MB);   // 16MB  [live: hrGEMM .. XT build]
  u16*   xt     = (u16*)(ws + 84 * MB);   // 48MB  [live: XT build .. Gram]
  u16*   hrin   = (u16*)(ws + 84 * MB);   // 24MB  overlay (dead before xt written)
  float* gparts = (float*)(ws + 4 * MB);  // 32MB  overlay h_bf (dead by then)
  u16*   g_bf   = (u16*)(ws + 68 * MB);   // 4MB   overlay hr_bf (dead by then)
  u16*   u_mat  = (u16*)(ws + 72 * MB);
  u16*   v1     = (u16*)(ws + 73 * MB);
  u16*   f2t    = (u16*)(ws + 77 * MB);

  // 1) f32 -> bf16 conversions
  cvt_f32_bf16<<<8192, 256, 0, stream>>>(h,    h_bf,  16777216L);
  cvt_f32_bf16<<<6144, 256, 0, stream>>>(hret, hrin,  12582912L);
  cvt_f32_bf16<<<192,  256, 0, stream>>>(Wc,   w_cond,  393216L);
  cvt_f32_bf16<<<128,  256, 0, stream>>>(Wa,   w_attn,  262144L);
  cvt_f32_bf16<<<128,  256, 0, stream>>>(Wk,   w_k,     262144L);
  cvt_f32_bf16<<<128,  256, 0, stream>>>(Wv,   w_v,     262144L);
  cvt_f32_bf16<<<128,  256, 0, stream>>>(Wo,   w_out,   262144L);

  // 2) W_v^T (for U = W_out @ W_v expressed as NT)
  transpose_bf16<<<dim3(8, 8, 1), 256, 0, stream>>>(w_v, w_vT, 512, 512, 0, 0);

  // 3) hr = h_retrieved @ W_cond^T   [16384 x 512, K=768]
  gemm_nt<0><<<dim3(128, 4, 1), 256, 0, stream>>>(hrin, w_cond, hr_bf, nullptr,
      768, 768, 768, 512, 0, 0, 0, 0, 0, 1);

  // 4) logits = h @ W_attn^T  [32768 x 512, K=512], then softmax in place -> attn
  gemm_nt<0><<<dim3(256, 4, 1), 256, 0, stream>>>(h_bf, w_attn, attn, nullptr,
      512, 512, 512, 512, 0, 0, 0, 0, 0, 1);
  softmax512<<<8192, 256, 0, stream>>>(attn);

  // 5) XT[b, d, n] = X[b, n, d],  X = [h ; hr]  (n: 0..4095 = h, 4096..6143 = hr)
  transpose_bf16<<<dim3(64, 8, 8), 256, 0, stream>>>(h_bf,  xt,        512, 6144, 2097152L, 3145728L);
  transpose_bf16<<<dim3(32, 8, 8), 256, 0, stream>>>(hr_bf, xt + 4096, 512, 6144, 1048576L, 3145728L);

  // 6) Gram G = X^T X via NT(XT, XT), split-K=4 into f32 partials, then reduce -> bf16
  gemm_nt<2><<<dim3(4, 4, 32), 256, 0, stream>>>(xt, xt, gparts, nullptr,
      1536, 6144, 6144, 512, 3145728L, 3145728L, 1048576L, 262144L, 0, 4);
  reduce4_bf16<<<2048, 256, 0, stream>>>(gparts, g_bf);

  // 7) f2^T = W_out W_v G W_k^T  (G symmetric):
  //    U = NT(W_out, W_vT) = W_out W_v ;  V1 = NT(U, G) = U G ;  f2T = NT(V1, W_k)
  gemm_nt<0><<<dim3(4, 4, 1), 256, 0, stream>>>(w_out, w_vT, u_mat, nullptr,
      512, 512, 512, 512, 0, 0, 0, 0, 0, 1);
  gemm_nt<0><<<dim3(4, 4, 8), 256, 0, stream>>>(u_mat, g_bf, v1, nullptr,
      512, 512, 512, 512, 0, 262144L, 262144L, 0, 0, 1);
  gemm_nt<0><<<dim3(4, 4, 8), 256, 0, stream>>>(v1, w_k, f2t, nullptr,
      512, 512, 512, 512, 262144L, 0, 262144L, 0, 0, 1);

  // 8) out = h + attn @ f2  via NT(attn, f2T) with fused residual, f32 out
  gemm_nt<1><<<dim3(32, 4, 8), 256, 0, stream>>>(attn, f2t, out, h,
      512, 512, 512, 512, 2097152L, 262144L, 2097152L, 0, 2097152L, 1);
}